// Round 1
// 1148.146 us; speedup vs baseline: 2.3339x; 2.3339x over previous
//
#include <hip/hip_runtime.h>
#include <cstddef>

#define N_DATA   500000
#define FEAT     128
#define KP1      4097
#define BSZ      256
#define SDIM     1024
#define TDIM     2048
#define EPS_     1e-7f

// workspace layout (float offsets)
#define WS_ES     0
#define WS_ET     (BSZ*FEAT)
#define WS_OUT_T  (2*BSZ*FEAT)
#define WS_OUT_S  (WS_OUT_T + BSZ*KP1)
#define WS_SUMS   (WS_OUT_S + BSZ*KP1)   // [0]=Zt_sum [1]=Zs_sum [2]=loss_sum

__global__ void init_kernel(float* __restrict__ sums) {
    if (threadIdx.x < 3) sums[threadIdx.x] = 0.0f;
}

// es = l2norm(f @ W + b). One block per batch row; 512 threads = feature (128) x K-slice (4).
__global__ void embed_kernel(const float* __restrict__ f, const float* __restrict__ W,
                             const float* __restrict__ bias, float* __restrict__ out, int D) {
    __shared__ float fs[TDIM];
    __shared__ float partial[512];
    __shared__ float red[128];
    int b = blockIdx.x, t = threadIdx.x;
    const float* frow = f + (size_t)b * D;
    for (int i = t; i < D; i += 512) fs[i] = frow[i];
    __syncthreads();
    int feat  = t & 127;
    int slice = t >> 7;            // 0..3
    int seg = D >> 2;
    int i0 = slice * seg, i1 = i0 + seg;
    float acc = 0.0f;
    #pragma unroll 4
    for (int i = i0; i < i1; ++i)
        acc = fmaf(fs[i], W[(size_t)i * FEAT + feat], acc);
    partial[t] = acc;
    __syncthreads();
    float s = 0.0f;
    if (t < 128) {
        s = partial[t] + partial[t + 128] + partial[t + 256] + partial[t + 384] + bias[t];
        red[t] = s * s;
    }
    __syncthreads();
    for (int off = 64; off > 0; off >>= 1) {
        if (t < off) red[t] += red[t + off];
        __syncthreads();
    }
    if (t < 128) out[(size_t)b * FEAT + t] = s * (1.0f / sqrtf(red[0]));
}

// Latency-optimized gather+dot: 16 lanes per row (8 floats/lane via 2x float4),
// 4 rows per wave-step, indices staged in LDS, 8 row-loads in flight per batch,
// 4 shfl_xor amortized over 4 rows, one Z atomic per block.
// Grid (16, BSZ): block handles k = [bx*256, bx*256+256) for batch row b. Covers k=0..4095.
__global__ __launch_bounds__(256)
void gather_dot_kernel(const float* __restrict__ mem, const float* __restrict__ e,
                       const int* __restrict__ cidx, float* __restrict__ out_arr,
                       float* __restrict__ zsum) {
    int b     = blockIdx.y;
    int kbase = blockIdx.x * 256;
    int t     = threadIdx.x;
    __shared__ int   sidx[256];
    __shared__ float red[256];
    sidx[t] = cidx[(size_t)b * KP1 + kbase + t];

    int lane = t & 63;
    int wave = t >> 6;         // 0..3
    int sub  = lane & 15;      // position within row (handles floats sub*4.. and 64+sub*4..)
    int g    = lane >> 4;      // which of 4 concurrent rows

    const float4* e4 = (const float4*)(e + (size_t)b * FEAT);
    float4 ef0 = e4[sub];
    float4 ef1 = e4[sub + 16];
    __syncthreads();

    float wsum = 0.0f;
    int jb0 = wave * 64;       // this wave's 64-k chunk within the block's 256
    for (int batch = 0; batch < 4; ++batch) {
        int rows[4];
        float4 va[4], vb[4];
        #pragma unroll
        for (int u = 0; u < 4; ++u)
            rows[u] = sidx[jb0 + batch * 16 + u * 4 + g];
        #pragma unroll
        for (int u = 0; u < 4; ++u) {
            const float4* p = (const float4*)(mem + (size_t)rows[u] * FEAT);
            va[u] = p[sub];
            vb[u] = p[sub + 16];
        }
        #pragma unroll
        for (int u = 0; u < 4; ++u) {
            float d0 = va[u].x * ef0.x + va[u].y * ef0.y + va[u].z * ef0.z + va[u].w * ef0.w;
            float d1 = vb[u].x * ef1.x + vb[u].y * ef1.y + vb[u].z * ef1.z + vb[u].w * ef1.w;
            float d  = d0 + d1;
            d += __shfl_xor(d, 8, 64);
            d += __shfl_xor(d, 4, 64);
            d += __shfl_xor(d, 2, 64);
            d += __shfl_xor(d, 1, 64);
            float o = expf(d * (1.0f / 0.07f));
            if (sub == 0) {
                out_arr[(size_t)b * KP1 + kbase + jb0 + batch * 16 + u * 4 + g] = o;
                wsum += o;
            }
        }
    }
    red[t] = wsum;
    __syncthreads();
    for (int off = 128; off > 0; off >>= 1) {
        if (t < off) red[t] += red[t + off];
        __syncthreads();
    }
    if (t == 0) atomicAdd(zsum, red[0]);
}

// Handles the straggler column k = 4096 for every batch row.
__global__ void gather_tail_kernel(const float* __restrict__ mem, const float* __restrict__ e,
                                   const int* __restrict__ cidx, float* __restrict__ out_arr,
                                   float* __restrict__ zsum) {
    int b = blockIdx.x;
    int lane = threadIdx.x;    // 64 threads
    int row = cidx[(size_t)b * KP1 + (KP1 - 1)];
    const float2 ef = *(const float2*)(e + (size_t)b * FEAT + 2 * lane);
    const float2 wv = *(const float2*)(mem + (size_t)row * FEAT + 2 * lane);
    float p = fmaf(wv.x, ef.x, wv.y * ef.y);
    #pragma unroll
    for (int off = 32; off > 0; off >>= 1) p += __shfl_xor(p, off, 64);
    float o = expf(p * (1.0f / 0.07f));
    if (lane == 0) {
        out_arr[(size_t)b * KP1 + (KP1 - 1)] = o;
        atomicAdd(zsum, o);
    }
}

__global__ void loss_kernel(const float* __restrict__ out_t, const float* __restrict__ out_s,
                            const float* __restrict__ sums, float* __restrict__ loss_accum) {
    const float scale = (float)N_DATA / (float)(BSZ * KP1);
    float iZt = 1.0f / (sums[0] * scale);
    float iZs = 1.0f / (sums[1] * scale);
    const float c = 4096.0f / (float)N_DATA;   // m * Pn
    float local = 0.0f;
    int total = BSZ * KP1;
    for (int i = blockIdx.x * blockDim.x + threadIdx.x; i < total;
         i += gridDim.x * blockDim.x) {
        int k = i - (i / KP1) * KP1;
        float xt = out_t[i] * iZt;
        float xs = out_s[i] * iZs;
        if (k == 0)
            local += logf(xt / (xt + c + EPS_)) + logf(xs / (xs + c + EPS_));
        else
            local += logf(c / (xt + c + EPS_)) + logf(c / (xs + c + EPS_));
    }
    __shared__ float red[256];
    red[threadIdx.x] = local;
    __syncthreads();
    for (int off = 128; off > 0; off >>= 1) {
        if ((int)threadIdx.x < off) red[threadIdx.x] += red[threadIdx.x + off];
        __syncthreads();
    }
    if (threadIdx.x == 0) atomicAdd(loss_accum, red[0]);
}

__global__ void finalize_kernel(const float* __restrict__ sums, float* __restrict__ out) {
    if (threadIdx.x == 0 && blockIdx.x == 0) out[0] = -sums[2] * (1.0f / (float)BSZ);
}

// dst = out+1 (+64M) is only 4B-aligned; dst+3 is 16B aligned. Scalar loads,
// vector (dwordx4) stores; head 3 floats + 1 tail float handled by thread 0.
__global__ void copy_kernel(const float* __restrict__ src, float* __restrict__ dst) {
    const size_t NCHUNK = 15999999ul;      // (64e6 - 4) / 4
    size_t stride = (size_t)gridDim.x * blockDim.x;
    for (size_t i = (size_t)blockIdx.x * blockDim.x + threadIdx.x; i < NCHUNK; i += stride) {
        size_t base = 3 + 4 * i;
        float4 v = make_float4(src[base], src[base + 1], src[base + 2], src[base + 3]);
        *reinterpret_cast<float4*>(dst + base) = v;
    }
    if (blockIdx.x == 0 && threadIdx.x == 0) {
        dst[0] = src[0]; dst[1] = src[1]; dst[2] = src[2];
        dst[63999999] = src[63999999];
    }
}

// Overwrite updated rows. "Last b wins" for duplicate idx (numpy/jax scatter-set order).
__global__ void scatter_kernel(const float* __restrict__ mem, const float* __restrict__ e,
                               const int* __restrict__ idx, float* __restrict__ dst) {
    int b = blockIdx.x, t = threadIdx.x;
    int my = idx[b];
    for (int b2 = b + 1; b2 < BSZ; ++b2)
        if (idx[b2] == my) return;         // uniform across block
    float nw = 0.5f * mem[(size_t)my * FEAT + t] + 0.5f * e[(size_t)b * FEAT + t];
    __shared__ float red[128];
    red[t] = nw * nw;
    __syncthreads();
    for (int off = 64; off > 0; off >>= 1) {
        if (t < off) red[t] += red[t + off];
        __syncthreads();
    }
    dst[(size_t)my * FEAT + t] = nw * (1.0f / sqrtf(red[0]));
}

extern "C" void kernel_launch(void* const* d_in, const int* in_sizes, int n_in,
                              void* d_out, int out_size, void* d_ws, size_t ws_size,
                              hipStream_t stream) {
    const float* f_s  = (const float*)d_in[0];
    const float* f_t  = (const float*)d_in[1];
    const int*   idx  = (const int*)d_in[2];
    const int*   cidx = (const int*)d_in[3];
    const float* W_s  = (const float*)d_in[4];
    const float* b_s  = (const float*)d_in[5];
    const float* W_t  = (const float*)d_in[6];
    const float* b_t  = (const float*)d_in[7];
    const float* m1   = (const float*)d_in[8];
    const float* m2   = (const float*)d_in[9];

    float* out = (float*)d_out;
    float* ws  = (float*)d_ws;
    float* es        = ws + WS_ES;
    float* et        = ws + WS_ET;
    float* out_t_arr = ws + WS_OUT_T;
    float* out_s_arr = ws + WS_OUT_S;
    float* sums      = ws + WS_SUMS;
    float* out1 = out + 1;
    float* out2 = out + 1 + (size_t)N_DATA * FEAT;

    hipLaunchKernelGGL(init_kernel, dim3(1), dim3(64), 0, stream, sums);
    hipLaunchKernelGGL(embed_kernel, dim3(BSZ), dim3(512), 0, stream, f_s, W_s, b_s, es, SDIM);
    hipLaunchKernelGGL(embed_kernel, dim3(BSZ), dim3(512), 0, stream, f_t, W_t, b_t, et, TDIM);
    // out_t uses memory_v1 with et; out_s uses memory_v2 with es.
    // Separate launches so each gather phase's ~260MB footprint fits the 256MB L3.
    hipLaunchKernelGGL(gather_dot_kernel, dim3(16, BSZ), dim3(256), 0, stream,
                       m1, et, cidx, out_t_arr, sums + 0);
    hipLaunchKernelGGL(gather_tail_kernel, dim3(BSZ), dim3(64), 0, stream,
                       m1, et, cidx, out_t_arr, sums + 0);
    hipLaunchKernelGGL(gather_dot_kernel, dim3(16, BSZ), dim3(256), 0, stream,
                       m2, es, cidx, out_s_arr, sums + 1);
    hipLaunchKernelGGL(gather_tail_kernel, dim3(BSZ), dim3(64), 0, stream,
                       m2, es, cidx, out_s_arr, sums + 1);
    hipLaunchKernelGGL(loss_kernel, dim3(1024), dim3(256), 0, stream,
                       out_t_arr, out_s_arr, sums, sums + 2);
    hipLaunchKernelGGL(finalize_kernel, dim3(1), dim3(64), 0, stream, sums, out);
    hipLaunchKernelGGL(copy_kernel, dim3(8192), dim3(256), 0, stream, m1, out1);
    hipLaunchKernelGGL(copy_kernel, dim3(8192), dim3(256), 0, stream, m2, out2);
    // memory_v1 updated with es; memory_v2 with et (note the cross vs the loss pairing).
    hipLaunchKernelGGL(scatter_kernel, dim3(BSZ), dim3(FEAT), 0, stream, m1, es, idx, out1);
    hipLaunchKernelGGL(scatter_kernel, dim3(BSZ), dim3(FEAT), 0, stream, m2, et, idx, out2);
}